// Round 7
// baseline (232.517 us; speedup 1.0000x reference)
//
#include <hip/hip_runtime.h>
#include <hip/hip_bf16.h>
#include <stdint.h>

#define B_    4
#define L_    2048
#define T_    8192      // B*L tokens
#define D_    1024
#define E_    8
#define H_    512

typedef __bf16  bf16x8 __attribute__((ext_vector_type(8)));
typedef float   f32x4  __attribute__((ext_vector_type(4)));
typedef unsigned short ushort_t;

__device__ __forceinline__ ushort_t f2bf(float f) {
    union { float f; unsigned u; } v; v.f = f;
    unsigned u = v.u;
    unsigned r = (u + 0x7fffu + ((u >> 16) & 1u)) >> 16;   // RNE
    return (ushort_t)r;
}

// Branchless GELU: erf via Abramowitz-Stegun 7.1.26 (|eps| < 1.5e-7).
__device__ __forceinline__ float gelu_fast(float v) {
    float x  = v * 0.70710678118654752f;
    float ax = fabsf(x);
    float t  = __builtin_amdgcn_rcpf(1.0f + 0.3275911f * ax);
    float y  = t * (0.254829592f +
               t * (-0.284496736f +
               t * (1.421413741f +
               t * (-1.453152027f +
               t * 1.061405429f))));
    float e  = __expf(-x * x);
    float er = 1.0f - y * e;               // erf(|x|)
    er = copysignf(er, x);
    return 0.5f * v * (1.0f + er);
}

// async global->LDS, 16B per lane; LDS dest = wave-uniform base + lane*16
__device__ __forceinline__ void gld_lds16(const void* g, void* l) {
    __attribute__((address_space(3))) uint32_t* lp =
        reinterpret_cast<__attribute__((address_space(3))) uint32_t*>(
            reinterpret_cast<uintptr_t>(l));
    const __attribute__((address_space(1))) uint32_t* gp =
        reinterpret_cast<const __attribute__((address_space(1))) uint32_t*>(
            reinterpret_cast<uintptr_t>(g));
    __builtin_amdgcn_global_load_lds(gp, lp, 16, 0, 0);
}

// ---------------------------------------------------------------------------
// Fused prep: weight transpose+cvt AND gating+x-cvt in ONE dispatch.
//   bid <  8192 : transpose tile       bid >= 8192 : gating block
// ---------------------------------------------------------------------------
__global__ __launch_bounds__(256) void prep_kernel(
    const float* __restrict__ w1, const float* __restrict__ w2,
    ushort_t* __restrict__ o1, ushort_t* __restrict__ o2,
    const float* __restrict__ x, const float* __restrict__ gw,
    const float* __restrict__ gb,
    int* __restrict__ eidx, float* __restrict__ gsel, ushort_t* __restrict__ xbf)
{
    __shared__ float smem[E_ * D_];           // 32 KB
    const int bid = blockIdx.x;
    const int tid = threadIdx.x;

    if (bid < 8192) {
        // ---- transpose + cvt ----
        float (*tile)[33] = reinterpret_cast<float(*)[33]>(smem);
        const int mz = bid >> 9;              // 0..15
        const int bxy = bid & 511;
        const float* src; ushort_t* dst; int C, R, sh;
        if (mz < E_) {
            src = w1 + (size_t)mz * D_ * H_; dst = o1 + (size_t)mz * D_ * H_;
            R = D_; C = H_; sh = 4;
        } else {
            const int m = mz - E_;
            src = w2 + (size_t)m * D_ * H_;  dst = o2 + (size_t)m * D_ * H_;
            R = H_; C = D_; sh = 5;
        }
        const int bx = bxy & ((1 << sh) - 1);
        const int by = bxy >> sh;
        const int r0 = by * 32, c0 = bx * 32;
        const int lr = tid >> 3;
        const int lc = (tid & 7) * 4;
        float4 v = *(const float4*)(src + (size_t)(r0 + lr) * C + c0 + lc);
        tile[lr][lc+0] = v.x; tile[lr][lc+1] = v.y;
        tile[lr][lc+2] = v.z; tile[lr][lc+3] = v.w;
        __syncthreads();
        ushort4 o;
        o.x = f2bf(tile[lc+0][lr]);
        o.y = f2bf(tile[lc+1][lr]);
        o.z = f2bf(tile[lc+2][lr]);
        o.w = f2bf(tile[lc+3][lr]);
        *(ushort4*)(dst + (size_t)(c0 + lr) * R + r0 + lc) = o;
        return;
    }

    // ---- gating + x cvt ----
    float (*gwT)[D_] = reinterpret_cast<float(*)[D_]>(smem);   // [8][1024]
    const int gbid = bid - 8192;

    #pragma unroll
    for (int it = 0; it < 8; ++it) {
        const int idx = it * 256 + tid;       // float4 index, 2048 total
        float4 v = *(const float4*)(gw + (size_t)idx * 4);
        const int row = idx >> 1;             // d
        const int col = (idx & 1) * 4;        // e base
        gwT[col+0][row] = v.x;
        gwT[col+1][row] = v.y;
        gwT[col+2][row] = v.z;
        gwT[col+3][row] = v.w;
    }
    __syncthreads();

    const int wave = tid >> 6;
    const int lane = tid & 63;

    #pragma unroll
    for (int it = 0; it < 2; ++it) {
        const int t = gbid * 8 + wave * 2 + it;
        const float* xr = x + (size_t)t * D_;
        ushort_t* xbr = xbf + (size_t)t * D_;

        float acc[E_];
        #pragma unroll
        for (int e = 0; e < E_; ++e) acc[e] = 0.f;

        #pragma unroll
        for (int j = 0; j < 4; ++j) {
            const int d = j * 256 + lane * 4;
            float4 xv = *(const float4*)(xr + d);
            ushort4 o;
            o.x = f2bf(xv.x); o.y = f2bf(xv.y); o.z = f2bf(xv.z); o.w = f2bf(xv.w);
            *(ushort4*)(xbr + d) = o;
            #pragma unroll
            for (int e = 0; e < E_; ++e) {
                float4 w = *(const float4*)(&gwT[e][d]);
                acc[e] += xv.x * w.x + xv.y * w.y + xv.z * w.z + xv.w * w.w;
            }
        }
        #pragma unroll
        for (int s = 1; s < 64; s <<= 1) {
            #pragma unroll
            for (int e = 0; e < E_; ++e)
                acc[e] += __shfl_xor(acc[e], s, 64);
        }
        if (lane == 0) {
            float v[E_];
            #pragma unroll
            for (int e = 0; e < E_; ++e) v[e] = acc[e] + gb[e];
            int i0 = 0;
            #pragma unroll
            for (int e = 1; e < E_; ++e) if (v[e] > v[i0]) i0 = e;
            int i1 = (i0 == 0) ? 1 : 0;
            #pragma unroll
            for (int e = 0; e < E_; ++e) if (e != i0 && v[e] > v[i1]) i1 = e;
            float g0 = 1.f / (1.f + expf(v[i1] - v[i0]));
            eidx[t] = i0 | (i1 << 8);
            gsel[t] = g0;
        }
    }
}

// ---------------------------------------------------------------------------
// Gating phase 2: bucketize (8 global atomics/block) + pack per-expert lists.
// ---------------------------------------------------------------------------
__global__ __launch_bounds__(256) void bucket_kernel(
    const int* __restrict__ eidx, const float* __restrict__ gsel,
    int* __restrict__ counts, int* __restrict__ btok, float* __restrict__ bgate)
{
    __shared__ int lcnt[E_];
    __shared__ int lbase[E_];
    const int tid = threadIdx.x;
    if (tid < E_) lcnt[tid] = 0;
    __syncthreads();
    const int t = blockIdx.x * 256 + tid;
    const int pk = eidx[t];
    const float g0 = gsel[t];
    const int i0 = pk & 0xff, i1 = (pk >> 8) & 0xff;
    const int p0 = atomicAdd(&lcnt[i0], 1);
    const int p1 = atomicAdd(&lcnt[i1], 1);
    __syncthreads();
    if (tid < E_) lbase[tid] = atomicAdd(&counts[tid], lcnt[tid]);
    __syncthreads();
    const int q0 = lbase[i0] + p0, q1 = lbase[i1] + p1;
    btok[i0 * T_ + q0] = t; bgate[i0 * T_ + q0] = g0;
    btok[i1 * T_ + q1] = t; bgate[i1 * T_ + q1] = 1.f - g0;
}

// ---------------------------------------------------------------------------
// Layer 1: gathered xbf [n_e,1024] @ W1t[e] ([H][D]) -> gelu -> hbuf bf16
// 64x128 tile, BK=64, depth-2 counted-vmcnt pipeline (r4 structure —
// measured local optimum: 128² and 64² tiles, 3-buffer, drain-0 all worse).
// grid: (T_/64=128, H/128=4, E)
// ---------------------------------------------------------------------------
__global__ __launch_bounds__(256) void mlp1_kernel(
    const ushort_t* __restrict__ xbf, const ushort_t* __restrict__ w1t,
    const float* __restrict__ b1,
    const int* __restrict__ counts,
    const int* __restrict__ btok, ushort_t* __restrict__ hbuf)
{
    const int e   = blockIdx.z;
    const int n_e = counts[e];
    const int m0  = blockIdx.x * 64;
    if (m0 >= n_e) return;
    int off = 0;
    for (int i = 0; i < e; ++i) off += counts[i];
    const int n0  = blockIdx.y * 128;

    __shared__ ushort_t As[2][64 * 64];
    __shared__ ushort_t Bs[2][128 * 64];

    const int tid  = threadIdx.x;
    const int lane = tid & 63;
    const int wave = tid >> 6;

    const int srow = tid >> 3;                    // 0..31
    const int cg   = (tid & 7) ^ (srow & 7);      // swizzled global col group

    const ushort_t* aptr[2];
    #pragma unroll
    for (int i = 0; i < 2; ++i) {
        int m = m0 + i * 32 + srow;
        int tok = btok[e * T_ + (m < n_e ? m : n_e - 1)];
        aptr[i] = xbf + (size_t)tok * D_ + cg * 8;
    }
    const ushort_t* w1e = w1t + (size_t)e * (H_ * D_);
    const ushort_t* bptr[4];
    #pragma unroll
    for (int i = 0; i < 4; ++i)
        bptr[i] = w1e + (size_t)(n0 + i * 32 + srow) * D_ + cg * 8;

    const int fm   = lane & 15;
    const int quad = lane >> 4;
    const int wm   = (wave & 1) * 32;     // 2 waves over M=64
    const int wn   = (wave >> 1) * 64;    // 2 waves over N=128

    f32x4 acc[2][4];
    #pragma unroll
    for (int i = 0; i < 2; ++i)
        #pragma unroll
        for (int j = 0; j < 4; ++j)
            { acc[i][j][0]=0.f; acc[i][j][1]=0.f; acc[i][j][2]=0.f; acc[i][j][3]=0.f; }

    #define STAGE1(bufi, koff)                                              \
        do {                                                                \
            char* al_ = (char*)(&As[bufi][0]) + (wave << 10);               \
            char* bl_ = (char*)(&Bs[bufi][0]) + (wave << 10);               \
            _Pragma("unroll")                                               \
            for (int i_ = 0; i_ < 2; ++i_)                                  \
                gld_lds16(aptr[i_] + (koff), al_ + (i_ << 12));             \
            _Pragma("unroll")                                               \
            for (int i_ = 0; i_ < 4; ++i_)                                  \
                gld_lds16(bptr[i_] + (koff), bl_ + (i_ << 12));             \
        } while (0)

    STAGE1(0, 0);
    __builtin_amdgcn_sched_barrier(0);
    STAGE1(1, 64);
    __builtin_amdgcn_sched_barrier(0);

    int buf = 0;
    for (int k0 = 0; k0 < D_; k0 += 64) {
        if (k0 + 64 < D_) asm volatile("s_waitcnt vmcnt(6)" ::: "memory");
        else              asm volatile("s_waitcnt vmcnt(0)" ::: "memory");
        __builtin_amdgcn_s_barrier();
        const char* Ab = (const char*)(&As[buf][0]);
        const char* Bb = (const char*)(&Bs[buf][0]);
        #pragma unroll
        for (int kk = 0; kk < 2; ++kk) {
            const int grp = kk * 4 + quad;
            bf16x8 af[2], bfr[4];
            #pragma unroll
            for (int i = 0; i < 2; ++i) {
                int ra = wm + i * 16 + fm;
                af[i]  = *(const bf16x8*)(Ab + ra * 128 + ((grp ^ (ra & 7)) << 4));
            }
            #pragma unroll
            for (int j = 0; j < 4; ++j) {
                int rb = wn + j * 16 + fm;
                bfr[j] = *(const bf16x8*)(Bb + rb * 128 + ((grp ^ (rb & 7)) << 4));
            }
            #pragma unroll
            for (int i = 0; i < 2; ++i)
                #pragma unroll
                for (int j = 0; j < 4; ++j)
                    acc[i][j] = __builtin_amdgcn_mfma_f32_16x16x32_bf16(af[i], bfr[j], acc[i][j], 0, 0, 0);
        }
        if (k0 + 128 < D_) {
            asm volatile("s_waitcnt lgkmcnt(0)" ::: "memory");
            __builtin_amdgcn_s_barrier();
            STAGE1(buf, k0 + 128);
            __builtin_amdgcn_sched_barrier(0);
        }
        buf ^= 1;
    }
    #undef STAGE1

    float bcol[4];
    #pragma unroll
    for (int j = 0; j < 4; ++j)
        bcol[j] = b1[e * H_ + n0 + wn + j * 16 + fm];
    #pragma unroll
    for (int i = 0; i < 2; ++i) {
        #pragma unroll
        for (int r = 0; r < 4; ++r) {
            int m = m0 + wm + i * 16 + quad * 4 + r;
            if (m >= n_e) continue;
            ushort_t* hrow = hbuf + (size_t)(off + m) * H_ + n0;
            #pragma unroll
            for (int j = 0; j < 4; ++j)
                hrow[wn + j * 16 + fm] = f2bf(gelu_fast(acc[i][j][r] + bcol[j]));
        }
    }
}

// ---------------------------------------------------------------------------
// Layer 2 + combine FUSED: hbuf [n_e,512] @ W2t[e] -> (acc+b2)*gate ->
// fp32 atomicAdd directly into out[token] (out zero-initialized at launch).
// Removes obuf (32MB W) + combine kernel (64MB R + 32MB W + launch).
// Each (e,pos) slot is written by exactly ONE block -> bias added once.
// grid: (128, D/128=8, E)
// ---------------------------------------------------------------------------
__global__ __launch_bounds__(256) void mlp2_kernel(
    const ushort_t* __restrict__ hbuf, const ushort_t* __restrict__ w2t,
    const float* __restrict__ b2,
    const int* __restrict__ counts,
    const int* __restrict__ btok, const float* __restrict__ bgate,
    float* __restrict__ out)
{
    const int e   = blockIdx.z;
    const int n_e = counts[e];
    const int m0  = blockIdx.x * 64;
    if (m0 >= n_e) return;
    int off = 0;
    for (int i = 0; i < e; ++i) off += counts[i];
    const int n0  = blockIdx.y * 128;

    __shared__ ushort_t As[2][64 * 64];
    __shared__ ushort_t Bs[2][128 * 64];

    const int tid  = threadIdx.x;
    const int lane = tid & 63;
    const int wave = tid >> 6;

    const int srow = tid >> 3;
    const int cg   = (tid & 7) ^ (srow & 7);

    const ushort_t* aptr[2];
    #pragma unroll
    for (int i = 0; i < 2; ++i)
        aptr[i] = hbuf + (size_t)(off + m0 + i * 32 + srow) * H_ + cg * 8;  // slack rows ok
    const ushort_t* w2e = w2t + (size_t)e * (D_ * H_);
    const ushort_t* bptr[4];
    #pragma unroll
    for (int i = 0; i < 4; ++i)
        bptr[i] = w2e + (size_t)(n0 + i * 32 + srow) * H_ + cg * 8;

    const int fm   = lane & 15;
    const int quad = lane >> 4;
    const int wm   = (wave & 1) * 32;
    const int wn   = (wave >> 1) * 64;

    f32x4 acc[2][4];
    #pragma unroll
    for (int i = 0; i < 2; ++i)
        #pragma unroll
        for (int j = 0; j < 4; ++j)
            { acc[i][j][0]=0.f; acc[i][j][1]=0.f; acc[i][j][2]=0.f; acc[i][j][3]=0.f; }

    #define STAGE2(bufi, koff)                                              \
        do {                                                                \
            char* al_ = (char*)(&As[bufi][0]) + (wave << 10);               \
            char* bl_ = (char*)(&Bs[bufi][0]) + (wave << 10);               \
            _Pragma("unroll")                                               \
            for (int i_ = 0; i_ < 2; ++i_)                                  \
                gld_lds16(aptr[i_] + (koff), al_ + (i_ << 12));             \
            _Pragma("unroll")                                               \
            for (int i_ = 0; i_ < 4; ++i_)                                  \
                gld_lds16(bptr[i_] + (koff), bl_ + (i_ << 12));             \
        } while (0)

    STAGE2(0, 0);
    __builtin_amdgcn_sched_barrier(0);
    STAGE2(1, 64);
    __builtin_amdgcn_sched_barrier(0);

    int buf = 0;
    for (int k0 = 0; k0 < H_; k0 += 64) {
        if (k0 + 64 < H_) asm volatile("s_waitcnt vmcnt(6)" ::: "memory");
        else              asm volatile("s_waitcnt vmcnt(0)" ::: "memory");
        __builtin_amdgcn_s_barrier();
        const char* Ab = (const char*)(&As[buf][0]);
        const char* Bb = (const char*)(&Bs[buf][0]);
        #pragma unroll
        for (int kk = 0; kk < 2; ++kk) {
            const int grp = kk * 4 + quad;
            bf16x8 af[2], bfr[4];
            #pragma unroll
            for (int i = 0; i < 2; ++i) {
                int ra = wm + i * 16 + fm;
                af[i]  = *(const bf16x8*)(Ab + ra * 128 + ((grp ^ (ra & 7)) << 4));
            }
            #pragma unroll
            for (int j = 0; j < 4; ++j) {
                int rb = wn + j * 16 + fm;
                bfr[j] = *(const bf16x8*)(Bb + rb * 128 + ((grp ^ (rb & 7)) << 4));
            }
            #pragma unroll
            for (int i = 0; i < 2; ++i)
                #pragma unroll
                for (int j = 0; j < 4; ++j)
                    acc[i][j] = __builtin_amdgcn_mfma_f32_16x16x32_bf16(af[i], bfr[j], acc[i][j], 0, 0, 0);
        }
        if (k0 + 128 < H_) {
            asm volatile("s_waitcnt lgkmcnt(0)" ::: "memory");
            __builtin_amdgcn_s_barrier();
            STAGE2(buf, k0 + 128);
            __builtin_amdgcn_sched_barrier(0);
        }
        buf ^= 1;
    }
    #undef STAGE2

    float bcol[4];
    #pragma unroll
    for (int j = 0; j < 4; ++j)
        bcol[j] = b2[e * D_ + n0 + wn + j * 16 + fm];
    #pragma unroll
    for (int i = 0; i < 2; ++i) {
        #pragma unroll
        for (int r = 0; r < 4; ++r) {
            int m = m0 + wm + i * 16 + quad * 4 + r;
            if (m >= n_e) continue;
            float g = bgate[e * T_ + m];
            const int tok = btok[e * T_ + m];
            float* orow = out + (size_t)tok * D_ + n0;
            #pragma unroll
            for (int j = 0; j < 4; ++j)
                atomicAdd(&orow[wn + j * 16 + fm], (acc[i][j][r] + bcol[j]) * g);
        }
    }
}

// ---------------------------------------------------------------------------
extern "C" void kernel_launch(void* const* d_in, const int* in_sizes, int n_in,
                              void* d_out, int out_size, void* d_ws, size_t ws_size,
                              hipStream_t stream)
{
    const float* x  = (const float*)d_in[0];
    const float* gw = (const float*)d_in[1];
    const float* gb = (const float*)d_in[2];
    const float* w1 = (const float*)d_in[3];
    const float* b1 = (const float*)d_in[4];
    const float* w2 = (const float*)d_in[5];
    const float* b2 = (const float*)d_in[6];
    float* out = (float*)d_out;

    // workspace layout
    char* ws = (char*)d_ws;
    int*   counts  = (int*)ws;                                   // 8 ints
    int*   btok    = (int*)(ws + 256);                           // E*T ints
    float* bgate   = (float*)(ws + 256 + (size_t)E_*T_*4);
    size_t p = 256 + 2ull * E_ * T_ * 4;
    int*      eidx = (int*)(ws + p);      p += (size_t)T_ * 4;
    float*    gsel = (float*)(ws + p);    p += (size_t)T_ * 4;
    ushort_t* xbf  = (ushort_t*)(ws + p); p += (size_t)T_*D_*2;      // bf16 x (16 MB)
    ushort_t* w1t  = (ushort_t*)(ws + p); p += (size_t)E_*H_*D_*2;   // bf16 [E][H][D] (8 MB)
    ushort_t* w2t  = (ushort_t*)(ws + p); p += (size_t)E_*D_*H_*2;   // bf16 [E][D][H] (8 MB)
    ushort_t* hbuf = (ushort_t*)(ws + p);                        // bf16 [2T+128][H] (16.5 MB)

    (void)hipMemsetAsync(counts, 0, 64, stream);
    (void)hipMemsetAsync(out, 0, (size_t)T_ * D_ * sizeof(float), stream);

    prep_kernel<<<8192 + T_/8, 256, 0, stream>>>(
        w1, w2, w1t, w2t, x, gw, gb, eidx, gsel, xbf);
    bucket_kernel<<<T_/256, 256, 0, stream>>>(eidx, gsel, counts, btok, bgate);
    mlp1_kernel<<<dim3(T_/64, H_/128, E_), 256, 0, stream>>>(
        xbf, w1t, b1, counts, btok, hbuf);
    mlp2_kernel<<<dim3(T_/64, D_/128, E_), 256, 0, stream>>>(
        hbuf, w2t, b2, counts, btok, bgate, out);
}

// Round 8
// 192.565 us; speedup vs baseline: 1.2075x; 1.2075x over previous
//
#include <hip/hip_runtime.h>
#include <hip/hip_bf16.h>
#include <stdint.h>

#define B_    4
#define L_    2048
#define T_    8192      // B*L tokens
#define D_    1024
#define E_    8
#define H_    512

typedef __bf16  bf16x8 __attribute__((ext_vector_type(8)));
typedef float   f32x4  __attribute__((ext_vector_type(4)));
typedef unsigned short ushort_t;

__device__ __forceinline__ ushort_t f2bf(float f) {
    union { float f; unsigned u; } v; v.f = f;
    unsigned u = v.u;
    unsigned r = (u + 0x7fffu + ((u >> 16) & 1u)) >> 16;   // RNE
    return (ushort_t)r;
}

// Branchless GELU: erf via Abramowitz-Stegun 7.1.26 (|eps| < 1.5e-7).
__device__ __forceinline__ float gelu_fast(float v) {
    float x  = v * 0.70710678118654752f;
    float ax = fabsf(x);
    float t  = __builtin_amdgcn_rcpf(1.0f + 0.3275911f * ax);
    float y  = t * (0.254829592f +
               t * (-0.284496736f +
               t * (1.421413741f +
               t * (-1.453152027f +
               t * 1.061405429f))));
    float e  = __expf(-x * x);
    float er = 1.0f - y * e;               // erf(|x|)
    er = copysignf(er, x);
    return 0.5f * v * (1.0f + er);
}

// async global->LDS, 16B per lane; LDS dest = wave-uniform base + lane*16
__device__ __forceinline__ void gld_lds16(const void* g, void* l) {
    __attribute__((address_space(3))) uint32_t* lp =
        reinterpret_cast<__attribute__((address_space(3))) uint32_t*>(
            reinterpret_cast<uintptr_t>(l));
    const __attribute__((address_space(1))) uint32_t* gp =
        reinterpret_cast<const __attribute__((address_space(1))) uint32_t*>(
            reinterpret_cast<uintptr_t>(g));
    __builtin_amdgcn_global_load_lds(gp, lp, 16, 0, 0);
}

// ---------------------------------------------------------------------------
// Fused prep: weight transpose+cvt AND gating+x-cvt in ONE dispatch.
//   bid <  8192 : transpose tile       bid >= 8192 : gating block
// ---------------------------------------------------------------------------
__global__ __launch_bounds__(256) void prep_kernel(
    const float* __restrict__ w1, const float* __restrict__ w2,
    ushort_t* __restrict__ o1, ushort_t* __restrict__ o2,
    const float* __restrict__ x, const float* __restrict__ gw,
    const float* __restrict__ gb,
    int* __restrict__ eidx, float* __restrict__ gsel, ushort_t* __restrict__ xbf)
{
    __shared__ float smem[E_ * D_];           // 32 KB
    const int bid = blockIdx.x;
    const int tid = threadIdx.x;

    if (bid < 8192) {
        // ---- transpose + cvt ----
        float (*tile)[33] = reinterpret_cast<float(*)[33]>(smem);
        const int mz = bid >> 9;              // 0..15
        const int bxy = bid & 511;
        const float* src; ushort_t* dst; int C, R, sh;
        if (mz < E_) {
            src = w1 + (size_t)mz * D_ * H_; dst = o1 + (size_t)mz * D_ * H_;
            R = D_; C = H_; sh = 4;
        } else {
            const int m = mz - E_;
            src = w2 + (size_t)m * D_ * H_;  dst = o2 + (size_t)m * D_ * H_;
            R = H_; C = D_; sh = 5;
        }
        const int bx = bxy & ((1 << sh) - 1);
        const int by = bxy >> sh;
        const int r0 = by * 32, c0 = bx * 32;
        const int lr = tid >> 3;
        const int lc = (tid & 7) * 4;
        float4 v = *(const float4*)(src + (size_t)(r0 + lr) * C + c0 + lc);
        tile[lr][lc+0] = v.x; tile[lr][lc+1] = v.y;
        tile[lr][lc+2] = v.z; tile[lr][lc+3] = v.w;
        __syncthreads();
        ushort4 o;
        o.x = f2bf(tile[lc+0][lr]);
        o.y = f2bf(tile[lc+1][lr]);
        o.z = f2bf(tile[lc+2][lr]);
        o.w = f2bf(tile[lc+3][lr]);
        *(ushort4*)(dst + (size_t)(c0 + lr) * R + r0 + lc) = o;
        return;
    }

    // ---- gating + x cvt ----
    float (*gwT)[D_] = reinterpret_cast<float(*)[D_]>(smem);   // [8][1024]
    const int gbid = bid - 8192;

    #pragma unroll
    for (int it = 0; it < 8; ++it) {
        const int idx = it * 256 + tid;       // float4 index, 2048 total
        float4 v = *(const float4*)(gw + (size_t)idx * 4);
        const int row = idx >> 1;             // d
        const int col = (idx & 1) * 4;        // e base
        gwT[col+0][row] = v.x;
        gwT[col+1][row] = v.y;
        gwT[col+2][row] = v.z;
        gwT[col+3][row] = v.w;
    }
    __syncthreads();

    const int wave = tid >> 6;
    const int lane = tid & 63;

    #pragma unroll
    for (int it = 0; it < 2; ++it) {
        const int t = gbid * 8 + wave * 2 + it;
        const float* xr = x + (size_t)t * D_;
        ushort_t* xbr = xbf + (size_t)t * D_;

        float acc[E_];
        #pragma unroll
        for (int e = 0; e < E_; ++e) acc[e] = 0.f;

        #pragma unroll
        for (int j = 0; j < 4; ++j) {
            const int d = j * 256 + lane * 4;
            float4 xv = *(const float4*)(xr + d);
            ushort4 o;
            o.x = f2bf(xv.x); o.y = f2bf(xv.y); o.z = f2bf(xv.z); o.w = f2bf(xv.w);
            *(ushort4*)(xbr + d) = o;
            #pragma unroll
            for (int e = 0; e < E_; ++e) {
                float4 w = *(const float4*)(&gwT[e][d]);
                acc[e] += xv.x * w.x + xv.y * w.y + xv.z * w.z + xv.w * w.w;
            }
        }
        #pragma unroll
        for (int s = 1; s < 64; s <<= 1) {
            #pragma unroll
            for (int e = 0; e < E_; ++e)
                acc[e] += __shfl_xor(acc[e], s, 64);
        }
        if (lane == 0) {
            float v[E_];
            #pragma unroll
            for (int e = 0; e < E_; ++e) v[e] = acc[e] + gb[e];
            int i0 = 0;
            #pragma unroll
            for (int e = 1; e < E_; ++e) if (v[e] > v[i0]) i0 = e;
            int i1 = (i0 == 0) ? 1 : 0;
            #pragma unroll
            for (int e = 0; e < E_; ++e) if (e != i0 && v[e] > v[i1]) i1 = e;
            float g0 = 1.f / (1.f + expf(v[i1] - v[i0]));
            eidx[t] = i0 | (i1 << 8);
            gsel[t] = g0;
        }
    }
}

// ---------------------------------------------------------------------------
// Gating phase 2: bucketize (8 global atomics/block) + pack (expert,pos) x2.
// ---------------------------------------------------------------------------
__global__ __launch_bounds__(256) void bucket_kernel(
    const int* __restrict__ eidx, const float* __restrict__ gsel,
    int* __restrict__ counts, int* __restrict__ btok, float* __restrict__ bgate,
    uint32_t* __restrict__ tpos)
{
    __shared__ int lcnt[E_];
    __shared__ int lbase[E_];
    const int tid = threadIdx.x;
    if (tid < E_) lcnt[tid] = 0;
    __syncthreads();
    const int t = blockIdx.x * 256 + tid;
    const int pk = eidx[t];
    const float g0 = gsel[t];
    const int i0 = pk & 0xff, i1 = (pk >> 8) & 0xff;
    const int p0 = atomicAdd(&lcnt[i0], 1);
    const int p1 = atomicAdd(&lcnt[i1], 1);
    __syncthreads();
    if (tid < E_) lbase[tid] = atomicAdd(&counts[tid], lcnt[tid]);
    __syncthreads();
    const int q0 = lbase[i0] + p0, q1 = lbase[i1] + p1;
    btok[i0 * T_ + q0] = t; bgate[i0 * T_ + q0] = g0;
    btok[i1 * T_ + q1] = t; bgate[i1 * T_ + q1] = 1.f - g0;
    tpos[t] = (uint32_t)((i0 << 13) | q0) | ((uint32_t)((i1 << 13) | q1) << 16);
}

// ---------------------------------------------------------------------------
// Layer 1: gathered xbf [n_e,1024] @ W1t[e] ([H][D]) -> gelu -> hbuf bf16
// 64x128 tile, BK=64, depth-2 counted-vmcnt pipeline (r4 local optimum).
// T1 XCD swizzle: 1D grid, expert = wgid % 8 -> each expert's whole
// working set (B 1MB + gathered A ~4MB) stays in ONE XCD's 4MB L2;
// converts panel re-reads from L3/HBM latency into L2 hits.
// grid: 4096 = 8 experts x 4 n-panels x 128 m-blocks
// ---------------------------------------------------------------------------
__global__ __launch_bounds__(256) void mlp1_kernel(
    const ushort_t* __restrict__ xbf, const ushort_t* __restrict__ w1t,
    const float* __restrict__ b1,
    const int* __restrict__ counts,
    const int* __restrict__ btok, ushort_t* __restrict__ hbuf)
{
    const int lid  = blockIdx.x;
    const int e    = lid & 7;              // expert pinned to XCD (dispatch %8)
    const int rest = lid >> 3;             // 0..511
    const int n0   = (rest >> 7) * 128;    // 4 panels
    const int m0   = (rest & 127) * 64;
    const int n_e  = counts[e];
    if (m0 >= n_e) return;
    int off = 0;
    for (int i = 0; i < e; ++i) off += counts[i];

    __shared__ ushort_t As[2][64 * 64];
    __shared__ ushort_t Bs[2][128 * 64];

    const int tid  = threadIdx.x;
    const int lane = tid & 63;
    const int wave = tid >> 6;

    const int srow = tid >> 3;                    // 0..31
    const int cg   = (tid & 7) ^ (srow & 7);      // swizzled global col group

    const ushort_t* aptr[2];
    #pragma unroll
    for (int i = 0; i < 2; ++i) {
        int m = m0 + i * 32 + srow;
        int tok = btok[e * T_ + (m < n_e ? m : n_e - 1)];
        aptr[i] = xbf + (size_t)tok * D_ + cg * 8;
    }
    const ushort_t* w1e = w1t + (size_t)e * (H_ * D_);
    const ushort_t* bptr[4];
    #pragma unroll
    for (int i = 0; i < 4; ++i)
        bptr[i] = w1e + (size_t)(n0 + i * 32 + srow) * D_ + cg * 8;

    const int fm   = lane & 15;
    const int quad = lane >> 4;
    const int wm   = (wave & 1) * 32;     // 2 waves over M=64
    const int wn   = (wave >> 1) * 64;    // 2 waves over N=128

    f32x4 acc[2][4];
    #pragma unroll
    for (int i = 0; i < 2; ++i)
        #pragma unroll
        for (int j = 0; j < 4; ++j)
            { acc[i][j][0]=0.f; acc[i][j][1]=0.f; acc[i][j][2]=0.f; acc[i][j][3]=0.f; }

    #define STAGE1(bufi, koff)                                              \
        do {                                                                \
            char* al_ = (char*)(&As[bufi][0]) + (wave << 10);               \
            char* bl_ = (char*)(&Bs[bufi][0]) + (wave << 10);               \
            _Pragma("unroll")                                               \
            for (int i_ = 0; i_ < 2; ++i_)                                  \
                gld_lds16(aptr[i_] + (koff), al_ + (i_ << 12));             \
            _Pragma("unroll")                                               \
            for (int i_ = 0; i_ < 4; ++i_)                                  \
                gld_lds16(bptr[i_] + (koff), bl_ + (i_ << 12));             \
        } while (0)

    STAGE1(0, 0);
    __builtin_amdgcn_sched_barrier(0);
    STAGE1(1, 64);
    __builtin_amdgcn_sched_barrier(0);

    int buf = 0;
    for (int k0 = 0; k0 < D_; k0 += 64) {
        if (k0 + 64 < D_) asm volatile("s_waitcnt vmcnt(6)" ::: "memory");
        else              asm volatile("s_waitcnt vmcnt(0)" ::: "memory");
        __builtin_amdgcn_s_barrier();
        const char* Ab = (const char*)(&As[buf][0]);
        const char* Bb = (const char*)(&Bs[buf][0]);
        #pragma unroll
        for (int kk = 0; kk < 2; ++kk) {
            const int grp = kk * 4 + quad;
            bf16x8 af[2], bfr[4];
            #pragma unroll
            for (int i = 0; i < 2; ++i) {
                int ra = wm + i * 16 + fm;
                af[i]  = *(const bf16x8*)(Ab + ra * 128 + ((grp ^ (ra & 7)) << 4));
            }
            #pragma unroll
            for (int j = 0; j < 4; ++j) {
                int rb = wn + j * 16 + fm;
                bfr[j] = *(const bf16x8*)(Bb + rb * 128 + ((grp ^ (rb & 7)) << 4));
            }
            #pragma unroll
            for (int i = 0; i < 2; ++i)
                #pragma unroll
                for (int j = 0; j < 4; ++j)
                    acc[i][j] = __builtin_amdgcn_mfma_f32_16x16x32_bf16(af[i], bfr[j], acc[i][j], 0, 0, 0);
        }
        if (k0 + 128 < D_) {
            asm volatile("s_waitcnt lgkmcnt(0)" ::: "memory");
            __builtin_amdgcn_s_barrier();
            STAGE1(buf, k0 + 128);
            __builtin_amdgcn_sched_barrier(0);
        }
        buf ^= 1;
    }
    #undef STAGE1

    float bcol[4];
    #pragma unroll
    for (int j = 0; j < 4; ++j)
        bcol[j] = b1[e * H_ + n0 + wn + j * 16 + fm];
    #pragma unroll
    for (int i = 0; i < 2; ++i) {
        #pragma unroll
        for (int r = 0; r < 4; ++r) {
            int m = m0 + wm + i * 16 + quad * 4 + r;
            if (m >= n_e) continue;
            ushort_t* hrow = hbuf + (size_t)(off + m) * H_ + n0;
            #pragma unroll
            for (int j = 0; j < 4; ++j)
                hrow[wn + j * 16 + fm] = f2bf(gelu_fast(acc[i][j][r] + bcol[j]));
        }
    }
}

// ---------------------------------------------------------------------------
// Layer 2: hbuf [n_e,512] @ W2t[e] ([D][H]) -> (acc+b2)*gate -> obuf bf16
// 64x128 tile, BK=64, counted-vmcnt depth-2 pipeline + T1 expert-per-XCD.
// grid: 8192 = 8 experts x 8 n-panels x 128 m-blocks
// ---------------------------------------------------------------------------
__global__ __launch_bounds__(256) void mlp2_kernel(
    const ushort_t* __restrict__ hbuf, const ushort_t* __restrict__ w2t,
    const float* __restrict__ b2,
    const int* __restrict__ counts,
    const float* __restrict__ bgate, ushort_t* __restrict__ obuf)
{
    const int lid  = blockIdx.x;
    const int e    = lid & 7;              // expert pinned to XCD
    const int rest = lid >> 3;             // 0..1023
    const int n0   = (rest >> 7) * 128;    // 8 panels
    const int m0   = (rest & 127) * 64;
    const int n_e  = counts[e];
    if (m0 >= n_e) return;
    int off = 0;
    for (int i = 0; i < e; ++i) off += counts[i];

    __shared__ ushort_t As[2][64 * 64];
    __shared__ ushort_t Bs[2][128 * 64];

    const int tid  = threadIdx.x;
    const int lane = tid & 63;
    const int wave = tid >> 6;

    const int srow = tid >> 3;
    const int cg   = (tid & 7) ^ (srow & 7);

    const ushort_t* aptr[2];
    #pragma unroll
    for (int i = 0; i < 2; ++i)
        aptr[i] = hbuf + (size_t)(off + m0 + i * 32 + srow) * H_ + cg * 8;  // slack rows ok
    const ushort_t* w2e = w2t + (size_t)e * (D_ * H_);
    const ushort_t* bptr[4];
    #pragma unroll
    for (int i = 0; i < 4; ++i)
        bptr[i] = w2e + (size_t)(n0 + i * 32 + srow) * H_ + cg * 8;

    const int fm   = lane & 15;
    const int quad = lane >> 4;
    const int wm   = (wave & 1) * 32;
    const int wn   = (wave >> 1) * 64;

    f32x4 acc[2][4];
    #pragma unroll
    for (int i = 0; i < 2; ++i)
        #pragma unroll
        for (int j = 0; j < 4; ++j)
            { acc[i][j][0]=0.f; acc[i][j][1]=0.f; acc[i][j][2]=0.f; acc[i][j][3]=0.f; }

    #define STAGE2(bufi, koff)                                              \
        do {                                                                \
            char* al_ = (char*)(&As[bufi][0]) + (wave << 10);               \
            char* bl_ = (char*)(&Bs[bufi][0]) + (wave << 10);               \
            _Pragma("unroll")                                               \
            for (int i_ = 0; i_ < 2; ++i_)                                  \
                gld_lds16(aptr[i_] + (koff), al_ + (i_ << 12));             \
            _Pragma("unroll")                                               \
            for (int i_ = 0; i_ < 4; ++i_)                                  \
                gld_lds16(bptr[i_] + (koff), bl_ + (i_ << 12));             \
        } while (0)

    STAGE2(0, 0);
    __builtin_amdgcn_sched_barrier(0);
    STAGE2(1, 64);
    __builtin_amdgcn_sched_barrier(0);

    int buf = 0;
    for (int k0 = 0; k0 < H_; k0 += 64) {
        if (k0 + 64 < H_) asm volatile("s_waitcnt vmcnt(6)" ::: "memory");
        else              asm volatile("s_waitcnt vmcnt(0)" ::: "memory");
        __builtin_amdgcn_s_barrier();
        const char* Ab = (const char*)(&As[buf][0]);
        const char* Bb = (const char*)(&Bs[buf][0]);
        #pragma unroll
        for (int kk = 0; kk < 2; ++kk) {
            const int grp = kk * 4 + quad;
            bf16x8 af[2], bfr[4];
            #pragma unroll
            for (int i = 0; i < 2; ++i) {
                int ra = wm + i * 16 + fm;
                af[i]  = *(const bf16x8*)(Ab + ra * 128 + ((grp ^ (ra & 7)) << 4));
            }
            #pragma unroll
            for (int j = 0; j < 4; ++j) {
                int rb = wn + j * 16 + fm;
                bfr[j] = *(const bf16x8*)(Bb + rb * 128 + ((grp ^ (rb & 7)) << 4));
            }
            #pragma unroll
            for (int i = 0; i < 2; ++i)
                #pragma unroll
                for (int j = 0; j < 4; ++j)
                    acc[i][j] = __builtin_amdgcn_mfma_f32_16x16x32_bf16(af[i], bfr[j], acc[i][j], 0, 0, 0);
        }
        if (k0 + 128 < H_) {
            asm volatile("s_waitcnt lgkmcnt(0)" ::: "memory");
            __builtin_amdgcn_s_barrier();
            STAGE2(buf, k0 + 128);
            __builtin_amdgcn_sched_barrier(0);
        }
        buf ^= 1;
    }
    #undef STAGE2

    float bcol[4];
    #pragma unroll
    for (int j = 0; j < 4; ++j)
        bcol[j] = b2[e * D_ + n0 + wn + j * 16 + fm];
    #pragma unroll
    for (int i = 0; i < 2; ++i) {
        #pragma unroll
        for (int r = 0; r < 4; ++r) {
            int m = m0 + wm + i * 16 + quad * 4 + r;
            if (m >= n_e) continue;
            float g = bgate[e * T_ + m];
            ushort_t* orow = obuf + (size_t)(off + m) * D_ + n0;
            #pragma unroll
            for (int j = 0; j < 4; ++j)
                orow[wn + j * 16 + fm] = f2bf((acc[i][j][r] + bcol[j]) * g);
        }
    }
}

// ---------------------------------------------------------------------------
// Combine: out[t] = obuf[slot0(t)] + obuf[slot1(t)].  Offsets recomputed
// from counts in-register -- no prefix kernel.
// ---------------------------------------------------------------------------
__global__ __launch_bounds__(256) void combine_kernel(
    const ushort_t* __restrict__ obuf, const uint32_t* __restrict__ tpos,
    const int* __restrict__ counts, float* __restrict__ out)
{
    const int tid = threadIdx.x;
    const int t = blockIdx.x * 2 + (tid >> 7);
    const int c = (tid & 127) * 8;
    const uint32_t pk = tpos[t];
    const int e0 = (pk >> 13) & 7, p0 = pk & 0x1fff;
    const int e1 = (pk >> 29) & 7, p1 = (pk >> 16) & 0x1fff;

    const int4 ca = *(const int4*)(counts);
    const int4 cb = *(const int4*)(counts + 4);
    int pre[8];
    pre[0] = 0;
    pre[1] = ca.x;
    pre[2] = pre[1] + ca.y;
    pre[3] = pre[2] + ca.z;
    pre[4] = pre[3] + ca.w;
    pre[5] = pre[4] + cb.x;
    pre[6] = pre[5] + cb.y;
    pre[7] = pre[6] + cb.z;
    int off0 = 0, off1 = 0;
    #pragma unroll
    for (int i = 1; i < 8; ++i) {
        off0 = (e0 == i) ? pre[i] : off0;
        off1 = (e1 == i) ? pre[i] : off1;
    }

    const size_t s0 = (size_t)(off0 + p0) * D_ + c;
    const size_t s1 = (size_t)(off1 + p1) * D_ + c;
    bf16x8 a = *(const bf16x8*)(obuf + s0);
    bf16x8 b = *(const bf16x8*)(obuf + s1);
    float4 o0, o1;
    o0.x = (float)a[0] + (float)b[0];
    o0.y = (float)a[1] + (float)b[1];
    o0.z = (float)a[2] + (float)b[2];
    o0.w = (float)a[3] + (float)b[3];
    o1.x = (float)a[4] + (float)b[4];
    o1.y = (float)a[5] + (float)b[5];
    o1.z = (float)a[6] + (float)b[6];
    o1.w = (float)a[7] + (float)b[7];
    float* orow = out + (size_t)t * D_ + c;
    *(float4*)(orow)     = o0;
    *(float4*)(orow + 4) = o1;
}

// ---------------------------------------------------------------------------
extern "C" void kernel_launch(void* const* d_in, const int* in_sizes, int n_in,
                              void* d_out, int out_size, void* d_ws, size_t ws_size,
                              hipStream_t stream)
{
    const float* x  = (const float*)d_in[0];
    const float* gw = (const float*)d_in[1];
    const float* gb = (const float*)d_in[2];
    const float* w1 = (const float*)d_in[3];
    const float* b1 = (const float*)d_in[4];
    const float* w2 = (const float*)d_in[5];
    const float* b2 = (const float*)d_in[6];
    float* out = (float*)d_out;

    // workspace layout
    char* ws = (char*)d_ws;
    int*   counts  = (int*)ws;                                   // 8 ints
    int*   btok    = (int*)(ws + 256);                           // E*T ints
    float* bgate   = (float*)(ws + 256 + (size_t)E_*T_*4);
    size_t p = 256 + 2ull * E_ * T_ * 4;
    int*      eidx = (int*)(ws + p);      p += (size_t)T_ * 4;
    float*    gsel = (float*)(ws + p);    p += (size_t)T_ * 4;
    uint32_t* tpos = (uint32_t*)(ws + p); p += (size_t)T_ * 4;
    ushort_t* xbf  = (ushort_t*)(ws + p); p += (size_t)T_*D_*2;      // bf16 x (16 MB)
    ushort_t* w1t  = (ushort_t*)(ws + p); p += (size_t)E_*H_*D_*2;   // bf16 [E][H][D] (8 MB)
    ushort_t* w2t  = (ushort_t*)(ws + p); p += (size_t)E_*D_*H_*2;   // bf16 [E][D][H] (8 MB)
    ushort_t* hbuf = (ushort_t*)(ws + p); p += ((size_t)2*T_+128)*H_*2; // bf16 (16.5 MB)
    ushort_t* obuf = (ushort_t*)(ws + p);                        // bf16 [2T+128][D] (33 MB)

    (void)hipMemsetAsync(counts, 0, 64, stream);

    prep_kernel<<<8192 + T_/8, 256, 0, stream>>>(
        w1, w2, w1t, w2t, x, gw, gb, eidx, gsel, xbf);
    bucket_kernel<<<T_/256, 256, 0, stream>>>(eidx, gsel, counts, btok, bgate, tpos);
    mlp1_kernel<<<4096, 256, 0, stream>>>(
        xbf, w1t, b1, counts, btok, hbuf);
    mlp2_kernel<<<8192, 256, 0, stream>>>(
        hbuf, w2t, b2, counts, bgate, obuf);
    combine_kernel<<<T_/2, 256, 0, stream>>>(obuf, tpos, counts, out);
}